// Round 1
// baseline (255.093 us; speedup 1.0000x reference)
//
#include <hip/hip_runtime.h>
#include <hip/hip_bf16.h>
#include <stdint.h>

#define NHEADS 12
#define HS 64
#define NB 8
#define NL 1024
#define ND 768
#define NE 1536
#define INFV 1000000000000.0f

typedef __bf16 bf16x8 __attribute__((ext_vector_type(8)));
typedef float f32x4 __attribute__((ext_vector_type(4)));

__device__ __forceinline__ unsigned short f2bf(float f) {
  unsigned int u = __builtin_bit_cast(unsigned int, f);
  u += 0x7fffu + ((u >> 16) & 1u);   // round-to-nearest-even
  return (unsigned short)(u >> 16);
}

__device__ __forceinline__ bf16x8 load_frag(const unsigned short* p) {
  uint4 v = *(const uint4*)p;
  return __builtin_bit_cast(bf16x8, v);
}

// ---- prep: x fp32 -> bf16 ----
__global__ __launch_bounds__(256) void k_prep_x(const float* __restrict__ x,
                                                unsigned short* __restrict__ xb, int n4) {
  int i = blockIdx.x * 256 + threadIdx.x;
  if (i >= n4) return;
  float4 v = ((const float4*)x)[i];
  ushort4 o;
  o.x = f2bf(v.x); o.y = f2bf(v.y); o.z = f2bf(v.z); o.w = f2bf(v.w);
  ((ushort4*)xb)[i] = o;
}

// ---- prep: W^T (NE x ND) bf16 ----
__global__ __launch_bounds__(256) void k_prep_wt(const float* __restrict__ W,
                                                 unsigned short* __restrict__ wt) {
  int e = blockIdx.x;
  for (int d = threadIdx.x; d < ND; d += 256)
    wt[e * ND + d] = f2bf(W[d * NE + e]);
}

// ---- prep: rope trig tables, 32 freqs per position ----
__global__ __launch_bounds__(64) void k_prep_trig(float* __restrict__ ct, float* __restrict__ st) {
  int p = blockIdx.x * 2 + (threadIdx.x >> 5);
  int i = threadIdx.x & 31;
  float inv = powf(10000.0f, -(float)i / 32.0f);
  float a = (float)p * inv;
  float sv, cv;
  sincosf(a, &sv, &cv);
  ct[p * 32 + i] = cv;
  st[p * 32 + i] = sv;
}

// ---- proj GEMM (x @ W + b) + RoPE, write q/k bf16 [96][1024][64] ----
__global__ __launch_bounds__(256) void k_proj_rope(
    const unsigned short* __restrict__ xb,   // [8192][768] bf16
    const unsigned short* __restrict__ wt,   // [1536][768] bf16 (W^T)
    const float* __restrict__ bias,          // [1536]
    const float* __restrict__ ct, const float* __restrict__ st,  // [1024][32]
    unsigned short* __restrict__ qbuf, unsigned short* __restrict__ kbuf) {
  const int h  = blockIdx.y;
  const int m0 = blockIdx.x * 128;
  const int e0 = h * 128;
  const int tid  = threadIdx.x;
  const int lane = tid & 63;
  const int w    = tid >> 6;
  const int wm = w >> 1, wn = w & 1;
  const int col_l = lane & 15, rq = lane >> 4;

  f32x4 acc[4][4];
  #pragma unroll
  for (int i = 0; i < 4; i++)
    #pragma unroll
    for (int j = 0; j < 4; j++)
      #pragma unroll
      for (int q = 0; q < 4; q++) acc[i][j][q] = 0.0f;

  const unsigned short* Abase = xb + (size_t)(m0 + wm * 64) * ND;
  const unsigned short* Bbase = wt + (size_t)(e0 + wn * 64) * ND;

  #pragma unroll 2
  for (int kk = 0; kk < ND; kk += 32) {
    bf16x8 af[4], bfr[4];
    #pragma unroll
    for (int f = 0; f < 4; f++) {
      af[f]  = load_frag(Abase + (size_t)(f * 16 + col_l) * ND + kk + rq * 8);
      bfr[f] = load_frag(Bbase + (size_t)(f * 16 + col_l) * ND + kk + rq * 8);
    }
    #pragma unroll
    for (int i = 0; i < 4; i++)
      #pragma unroll
      for (int j = 0; j < 4; j++)
        acc[i][j] = __builtin_amdgcn_mfma_f32_16x16x32_bf16(af[i], bfr[j], acc[i][j], 0, 0, 0);
  }

  // epilogue: bias + rope + store bf16
  #pragma unroll
  for (int fn = 0; fn < 4; fn++) {
    int nl   = wn * 64 + fn * 16 + col_l;   // 0..127 within head cols
    int s    = nl & 63;
    bool isk = nl >= 64;
    float bv  = bias[e0 + nl];
    float sgn = (s & 1) ? 1.0f : -1.0f;
    int   si  = s >> 1;
    #pragma unroll
    for (int fm = 0; fm < 4; fm++) {
      #pragma unroll
      for (int j = 0; j < 4; j++) {
        int m   = m0 + wm * 64 + fm * 16 + rq * 4 + j;
        int pos = m & (NL - 1);
        int bb  = m >> 10;
        float v = acc[fm][fn][j] + bv;
        float p = __shfl_xor(v, 1);          // partner column (even<->odd)
        float c = ct[pos * 32 + si];
        float sn = st[pos * 32 + si];
        float o = v * c + sgn * p * sn;      // out[2i]=v*c - v[2i+1]*s ; out[2i+1]=v*c + v[2i]*s
        size_t idx = (((size_t)(bb * NHEADS + h) * NL + pos) * HS + s);
        (isk ? kbuf : qbuf)[idx] = f2bf(o);
      }
    }
  }
}

// ---- logits: per (b,h) Q @ K^T with masks, /8 ----
__global__ __launch_bounds__(256) void k_logits(
    const unsigned short* __restrict__ qbuf,
    const unsigned short* __restrict__ kbuf,
    const int* __restrict__ mask,
    float* __restrict__ out) {
  const int bh = blockIdx.z;
  const int b  = bh / NHEADS;
  const int tn = blockIdx.x, tm = blockIdx.y;
  const int tid  = threadIdx.x;
  const int lane = tid & 63;
  const int w    = tid >> 6;
  const int wm = w >> 1, wn = w & 1;
  const int m_base = tm * 128 + wm * 64;
  const int n_base = tn * 128 + wn * 64;
  const int col_l = lane & 15, rq = lane >> 4;
  const unsigned short* Q = qbuf + (size_t)bh * (NL * HS);
  const unsigned short* K = kbuf + (size_t)bh * (NL * HS);

  f32x4 acc[4][4];
  #pragma unroll
  for (int i = 0; i < 4; i++)
    #pragma unroll
    for (int j = 0; j < 4; j++)
      #pragma unroll
      for (int q = 0; q < 4; q++) acc[i][j][q] = 0.0f;

  #pragma unroll
  for (int ks = 0; ks < 2; ks++) {
    bf16x8 aq[4], bk[4];
    #pragma unroll
    for (int f = 0; f < 4; f++) {
      aq[f] = load_frag(Q + (size_t)(m_base + f * 16 + col_l) * HS + ks * 32 + rq * 8);
      bk[f] = load_frag(K + (size_t)(n_base + f * 16 + col_l) * HS + ks * 32 + rq * 8);
    }
    #pragma unroll
    for (int i = 0; i < 4; i++)
      #pragma unroll
      for (int j = 0; j < 4; j++)
        acc[i][j] = __builtin_amdgcn_mfma_f32_16x16x32_bf16(aq[i], bk[j], acc[i][j], 0, 0, 0);
  }

  #pragma unroll
  for (int fn = 0; fn < 4; fn++) {
    int n = n_base + fn * 16 + col_l;
    float mc = (float)mask[b * NL + n];
    #pragma unroll
    for (int fm = 0; fm < 4; fm++) {
      #pragma unroll
      for (int j = 0; j < 4; j++) {
        int m = m_base + fm * 16 + rq * 4 + j;
        float mr = (float)mask[b * NL + m];
        float v = acc[fm][fn][j];
        v = v * mr - INFV * (1.0f - mr);
        v = v * mc - INFV * (1.0f - mc);
        if (n < m) v -= INFV;
        out[((size_t)bh * NL + m) * NL + n] = v * 0.125f;
      }
    }
  }
}

extern "C" void kernel_launch(void* const* d_in, const int* in_sizes, int n_in,
                              void* d_out, int out_size, void* d_ws, size_t ws_size,
                              hipStream_t stream) {
  const float* x    = (const float*)d_in[0];
  const float* W    = (const float*)d_in[1];
  const float* bias = (const float*)d_in[2];
  const int*   mask = (const int*)d_in[3];
  float* out = (float*)d_out;
  char* ws = (char*)d_ws;

  // workspace layout (bytes)
  unsigned short* xb = (unsigned short*)(ws);              // 8192*768*2    = 12,582,912
  unsigned short* wt = (unsigned short*)(ws + 12582912);   // 1536*768*2    =  2,359,296
  unsigned short* qb = (unsigned short*)(ws + 14942208);   // 96*1024*64*2  = 12,582,912
  unsigned short* kb = (unsigned short*)(ws + 27525120);   // 96*1024*64*2  = 12,582,912
  float* ct = (float*)(ws + 40108032);                     // 1024*32*4     =    131,072
  float* st = (float*)(ws + 40239104);                     // 1024*32*4     =    131,072

  k_prep_x<<<6144, 256, 0, stream>>>(x, xb, (NB * NL * ND) / 4);
  k_prep_wt<<<NE, 256, 0, stream>>>(W, wt);
  k_prep_trig<<<NL / 2, 64, 0, stream>>>(ct, st);
  k_proj_rope<<<dim3(64, 12), 256, 0, stream>>>(xb, wt, bias, ct, st, qb, kb);
  k_logits<<<dim3(8, 8, 96), 256, 0, stream>>>(qb, kb, mask, out);
}

// Round 3
// 206.490 us; speedup vs baseline: 1.2354x; 1.2354x over previous
//
#include <hip/hip_runtime.h>
#include <hip/hip_bf16.h>
#include <stdint.h>

#define NHEADS 12
#define HS 64
#define NB 8
#define NL 1024
#define ND 768
#define NE 1536
#define INFV 1000000000000.0f

typedef __bf16 bf16x8 __attribute__((ext_vector_type(8)));
typedef float f32x4 __attribute__((ext_vector_type(4)));

__device__ __forceinline__ unsigned short f2bf(float f) {
  unsigned int u = __builtin_bit_cast(unsigned int, f);
  u += 0x7fffu + ((u >> 16) & 1u);   // round-to-nearest-even
  return (unsigned short)(u >> 16);
}

__device__ __forceinline__ bf16x8 load_frag(const unsigned short* p) {
  uint4 v = *(const uint4*)p;
  return __builtin_bit_cast(bf16x8, v);
}

// ---- fused prep: x->bf16 | W transpose->bf16 | rope trig tables ----
// blocks [0,6144): x cvt; [6144,6432): W^T 64x64 tiles; [6432,6560): trig
__global__ __launch_bounds__(256) void k_prep(
    const float* __restrict__ x, const float* __restrict__ W,
    unsigned short* __restrict__ xb, unsigned short* __restrict__ wt,
    float* __restrict__ ct, float* __restrict__ st) {
  const int blk = blockIdx.x;
  if (blk < 6144) {
    int i = blk * 256 + threadIdx.x;
    float4 v = ((const float4*)x)[i];
    ushort4 o;
    o.x = f2bf(v.x); o.y = f2bf(v.y); o.z = f2bf(v.z); o.w = f2bf(v.w);
    ((ushort4*)xb)[i] = o;
  } else if (blk < 6144 + 288) {
    __shared__ float tile[64][65];
    int t = blk - 6144;
    int te = t % 24, td = t / 24;          // e-tile (1536/64), d-tile (768/64)
    int c = threadIdx.x & 63, r4 = threadIdx.x >> 6;
    #pragma unroll
    for (int rr = 0; rr < 16; rr++) {
      int row = rr * 4 + r4;               // d index within tile
      tile[row][c] = W[(size_t)(td * 64 + row) * NE + te * 64 + c];
    }
    __syncthreads();
    #pragma unroll
    for (int rr = 0; rr < 16; rr++) {
      int row = rr * 4 + r4;               // e index within tile
      wt[(size_t)(te * 64 + row) * ND + td * 64 + c] = f2bf(tile[c][row]);
    }
  } else {
    int t = (blk - 6432) * 256 + threadIdx.x;   // 32768 = 1024*32
    int p = t >> 5, i = t & 31;
    float inv = powf(10000.0f, -(float)i / 32.0f);
    float sv, cv;
    sincosf((float)p * inv, &sv, &cv);
    ct[p * 32 + i] = cv;
    st[p * 32 + i] = sv;
  }
}

// ---- proj GEMM (x @ W + b) + RoPE, write q/k bf16 [96][1024][64] ----
// A-operand = W^T rows (e), B-operand = x rows (m)  =>  D[e][m]:
// per thread: e = frag*16 + (lane>>4)*4 + reg (4 consecutive), m = lane&15.
// RoPE pairs (2i,2i+1) are in-thread; stores are ushort4.
__global__ __launch_bounds__(256) void k_proj_rope(
    const unsigned short* __restrict__ xb,   // [8192][768] bf16
    const unsigned short* __restrict__ wt,   // [1536][768] bf16 (W^T)
    const float* __restrict__ bias,          // [1536]
    const float* __restrict__ ct, const float* __restrict__ st,  // [1024][32]
    unsigned short* __restrict__ qbuf, unsigned short* __restrict__ kbuf) {
  const int h  = blockIdx.y;
  const int m0 = blockIdx.x * 128;
  const int e0 = h * 128;
  const int tid  = threadIdx.x;
  const int lane = tid & 63;
  const int w    = tid >> 6;
  const int wm = w >> 1, wn = w & 1;
  const int col_l = lane & 15, rq = lane >> 4;

  f32x4 acc[4][4];   // [e-frag][m-frag]
  #pragma unroll
  for (int i = 0; i < 4; i++)
    #pragma unroll
    for (int j = 0; j < 4; j++)
      #pragma unroll
      for (int q = 0; q < 4; q++) acc[i][j][q] = 0.0f;

  const unsigned short* Abase = wt + (size_t)(e0 + wn * 64) * ND;
  const unsigned short* Bbase = xb + (size_t)(m0 + wm * 64) * ND;

  #pragma unroll 2
  for (int kk = 0; kk < ND; kk += 32) {
    bf16x8 af[4], bfr[4];
    #pragma unroll
    for (int f = 0; f < 4; f++) {
      af[f]  = load_frag(Abase + (size_t)(f * 16 + col_l) * ND + kk + rq * 8);
      bfr[f] = load_frag(Bbase + (size_t)(f * 16 + col_l) * ND + kk + rq * 8);
    }
    #pragma unroll
    for (int i = 0; i < 4; i++)
      #pragma unroll
      for (int j = 0; j < 4; j++)
        acc[i][j] = __builtin_amdgcn_mfma_f32_16x16x32_bf16(af[i], bfr[j], acc[i][j], 0, 0, 0);
  }

  // epilogue: bias + rope (in-thread pairs) + ushort4 stores
  unsigned short* obuf = (wn == 1) ? kbuf : qbuf;   // wave-uniform
  #pragma unroll
  for (int i = 0; i < 4; i++) {
    const int s0  = i * 16 + rq * 4;                 // head-dim offset (mult of 4)
    const int si0 = s0 >> 1;
    float4 bv = *(const float4*)&bias[e0 + wn * 64 + s0];
    #pragma unroll
    for (int j = 0; j < 4; j++) {
      int m   = m0 + wm * 64 + j * 16 + col_l;
      int pos = m & (NL - 1);
      int bb  = m >> 10;
      float c0 = ct[pos * 32 + si0],     n0 = st[pos * 32 + si0];
      float c1 = ct[pos * 32 + si0 + 1], n1 = st[pos * 32 + si0 + 1];
      float v0 = acc[i][j][0] + bv.x;
      float v1 = acc[i][j][1] + bv.y;
      float v2 = acc[i][j][2] + bv.z;
      float v3 = acc[i][j][3] + bv.w;
      ushort4 o;
      o.x = f2bf(v0 * c0 - v1 * n0);
      o.y = f2bf(v1 * c0 + v0 * n0);
      o.z = f2bf(v2 * c1 - v3 * n1);
      o.w = f2bf(v3 * c1 + v2 * n1);
      *(ushort4*)&obuf[(((size_t)(bb * NHEADS + h)) * NL + pos) * HS + s0] = o;
    }
  }
}

// ---- logits: per (b,h) Q @ K^T with masks, /8 ----
// A-operand = K rows (n), B-operand = Q rows (m)  =>  D[n][m]:
// per thread: n = frag*16 + (lane>>4)*4 + reg (4 consecutive), m = lane&15
// -> 16B nontemporal stores along n.
__global__ __launch_bounds__(256) void k_logits(
    const unsigned short* __restrict__ qbuf,
    const unsigned short* __restrict__ kbuf,
    const int* __restrict__ mask,
    float* __restrict__ out) {
  const int bh = blockIdx.z;
  const int b  = bh / NHEADS;
  const int tn = blockIdx.x, tm = blockIdx.y;
  const int tid  = threadIdx.x;
  const int lane = tid & 63;
  const int w    = tid >> 6;
  const int wm = w >> 1, wn = w & 1;
  const int m_base = tm * 128 + wm * 64;
  const int n_base = tn * 128 + wn * 64;
  const int col_l = lane & 15, rq = lane >> 4;
  const unsigned short* Q = qbuf + (size_t)bh * (NL * HS);
  const unsigned short* K = kbuf + (size_t)bh * (NL * HS);
  const int* mrow = mask + b * NL;

  f32x4 acc[4][4];   // [n-frag][m-frag]
  #pragma unroll
  for (int i = 0; i < 4; i++)
    #pragma unroll
    for (int j = 0; j < 4; j++)
      #pragma unroll
      for (int q = 0; q < 4; q++) acc[i][j][q] = 0.0f;

  #pragma unroll
  for (int ks = 0; ks < 2; ks++) {
    bf16x8 ak[4], bq[4];
    #pragma unroll
    for (int f = 0; f < 4; f++) {
      ak[f] = load_frag(K + (size_t)(n_base + f * 16 + col_l) * HS + ks * 32 + rq * 8);
      bq[f] = load_frag(Q + (size_t)(m_base + f * 16 + col_l) * HS + ks * 32 + rq * 8);
    }
    #pragma unroll
    for (int i = 0; i < 4; i++)
      #pragma unroll
      for (int j = 0; j < 4; j++)
        acc[i][j] = __builtin_amdgcn_mfma_f32_16x16x32_bf16(ak[i], bq[j], acc[i][j], 0, 0, 0);
  }

  #pragma unroll
  for (int j = 0; j < 4; j++) {            // m-frags
    const int m = m_base + j * 16 + col_l;
    const bool mr0 = (mrow[m] == 0);       // per-thread uniform
    float* orow = out + ((size_t)bh * NL + m) * NL;
    #pragma unroll
    for (int i = 0; i < 4; i++) {          // n-frags
      const int n0 = n_base + i * 16 + rq * 4;
      int4 mc = *(const int4*)&mrow[n0];
      f32x4 o = acc[i][j];
      if (mr0) { o[0] = -INFV; o[1] = -INFV; o[2] = -INFV; o[3] = -INFV; }
      if (mc.x == 0) o[0] = -INFV;
      if (mc.y == 0) o[1] = -INFV;
      if (mc.z == 0) o[2] = -INFV;
      if (mc.w == 0) o[3] = -INFV;
      if (n0 + 0 < m) o[0] -= INFV;
      if (n0 + 1 < m) o[1] -= INFV;
      if (n0 + 2 < m) o[2] -= INFV;
      if (n0 + 3 < m) o[3] -= INFV;
      o *= 0.125f;
      __builtin_nontemporal_store(o, (f32x4*)(orow + n0));
    }
  }
}

extern "C" void kernel_launch(void* const* d_in, const int* in_sizes, int n_in,
                              void* d_out, int out_size, void* d_ws, size_t ws_size,
                              hipStream_t stream) {
  const float* x    = (const float*)d_in[0];
  const float* W    = (const float*)d_in[1];
  const float* bias = (const float*)d_in[2];
  const int*   mask = (const int*)d_in[3];
  float* out = (float*)d_out;
  char* ws = (char*)d_ws;

  unsigned short* xb = (unsigned short*)(ws);              // 12,582,912 B
  unsigned short* wt = (unsigned short*)(ws + 12582912);   //  2,359,296 B
  unsigned short* qb = (unsigned short*)(ws + 14942208);   // 12,582,912 B
  unsigned short* kb = (unsigned short*)(ws + 27525120);   // 12,582,912 B
  float* ct = (float*)(ws + 40108032);                     //    131,072 B
  float* st = (float*)(ws + 40239104);                     //    131,072 B

  k_prep<<<6560, 256, 0, stream>>>(x, W, xb, wt, ct, st);
  k_proj_rope<<<dim3(64, 12), 256, 0, stream>>>(xb, wt, bias, ct, st, qb, kb);
  k_logits<<<dim3(8, 8, 96), 256, 0, stream>>>(qb, kb, mask, out);
}

// Round 4
// 172.028 us; speedup vs baseline: 1.4829x; 1.2003x over previous
//
#include <hip/hip_runtime.h>
#include <hip/hip_bf16.h>
#include <stdint.h>

#define NHEADS 12
#define HS 64
#define NB 8
#define NL 1024
#define ND 768
#define NE 1536
#define INFV 1000000000000.0f

typedef __bf16 bf16x8 __attribute__((ext_vector_type(8)));
typedef float f32x4 __attribute__((ext_vector_type(4)));

typedef __attribute__((address_space(1))) const unsigned int gas_uint;
typedef __attribute__((address_space(3))) unsigned int las_uint;
#define GLOAD_LDS16(g, l) __builtin_amdgcn_global_load_lds((gas_uint*)(g), (las_uint*)(l), 16, 0, 0)

__device__ __forceinline__ unsigned short f2bf(float f) {
  unsigned int u = __builtin_bit_cast(unsigned int, f);
  u += 0x7fffu + ((u >> 16) & 1u);   // round-to-nearest-even
  return (unsigned short)(u >> 16);
}

__device__ __forceinline__ bf16x8 load_frag(const unsigned short* p) {
  uint4 v = *(const uint4*)p;
  return __builtin_bit_cast(bf16x8, v);
}

// ---- fused prep: x->bf16 | W transpose->bf16 | rope trig tables ----
__global__ __launch_bounds__(256) void k_prep(
    const float* __restrict__ x, const float* __restrict__ W,
    unsigned short* __restrict__ xb, unsigned short* __restrict__ wt,
    float* __restrict__ ct, float* __restrict__ st) {
  const int blk = blockIdx.x;
  if (blk < 6144) {
    int i = blk * 256 + threadIdx.x;
    float4 v = ((const float4*)x)[i];
    ushort4 o;
    o.x = f2bf(v.x); o.y = f2bf(v.y); o.z = f2bf(v.z); o.w = f2bf(v.w);
    ((ushort4*)xb)[i] = o;
  } else if (blk < 6144 + 288) {
    __shared__ float tile[64][65];
    int t = blk - 6144;
    int te = t % 24, td = t / 24;
    int c = threadIdx.x & 63, r4 = threadIdx.x >> 6;
    #pragma unroll
    for (int rr = 0; rr < 16; rr++) {
      int row = rr * 4 + r4;
      tile[row][c] = W[(size_t)(td * 64 + row) * NE + te * 64 + c];
    }
    __syncthreads();
    #pragma unroll
    for (int rr = 0; rr < 16; rr++) {
      int row = rr * 4 + r4;
      wt[(size_t)(te * 64 + row) * ND + td * 64 + c] = f2bf(tile[c][row]);
    }
  } else {
    int t = (blk - 6432) * 256 + threadIdx.x;
    int p = t >> 5, i = t & 31;
    float inv = powf(10000.0f, -(float)i / 32.0f);
    float sv, cv;
    sincosf((float)p * inv, &sv, &cv);
    ct[p * 32 + i] = cv;
    st[p * 32 + i] = sv;
  }
}

// ---- proj GEMM (x @ W + b) + RoPE  — m97-style LDS staging, BK=64 ----
// A-operand = W^T rows (e), B-operand = x rows (m)  =>  D[e][m].
// LDS: A tile [128e][64k] bf16 @ 0, B tile [128m][64k] @ 16384 bytes.
// XOR swizzle: 16B slot s of row r stored at phys slot s^(r&7) —
// applied by pre-swizzling the GLOBAL source (linear gload_lds dest)
// and the same XOR on the ds_read address (rule #21 both-sides).
__global__ __launch_bounds__(256) void k_proj_rope(
    const unsigned short* __restrict__ xb,   // [8192][768] bf16
    const unsigned short* __restrict__ wt,   // [1536][768] bf16 (W^T)
    const float* __restrict__ bias,          // [1536]
    const float* __restrict__ ct, const float* __restrict__ st,  // [1024][32]
    unsigned short* __restrict__ qbuf, unsigned short* __restrict__ kbuf) {
  const int h  = blockIdx.y;
  const int m0 = blockIdx.x * 128;
  const int e0 = h * 128;
  const int tid  = threadIdx.x;
  const int lane = tid & 63;
  const int w    = tid >> 6;
  const int wm = w >> 1, wn = w & 1;
  const int col_l = lane & 15, rq = lane >> 4;

  __shared__ unsigned short smem[16384];     // 32 KB: A[0,16K) B[16K,32K)
  char* smem_b = (char*)smem;

  // staging: 1024 chunks/tile (row r=p>>3, phys slot sl=p&7), 4 insts/thread
  unsigned int goff[4], loff[4];
  #pragma unroll
  for (int q = 0; q < 4; q++) {
    int p  = q * 256 + tid;
    int r  = p >> 3, sl = p & 7;
    int s  = sl ^ (r & 7);                   // inverse-swizzled source slot
    goff[q] = r * ND + s * 8;                // element offset within tile cols
    loff[q] = p * 16;                        // linear LDS byte offset
  }
  const unsigned short* gA = wt + (size_t)e0 * ND;
  const unsigned short* gB = xb + (size_t)m0 * ND;

  // ds_read bases (phys byte): row R, logical slot s -> R*128 + (s^(R&7))*16
  // A rows: R = wn*64 + f*16 + col_l  (R&7 == col_l&7), f term = +2048*f
  const int xr = col_l & 7;
  const unsigned int aB0 = (unsigned)((wn * 64 + col_l) * 128 + ((0 * 4 + rq) ^ xr) * 16);
  const unsigned int aB1 = (unsigned)((wn * 64 + col_l) * 128 + ((1 * 4 + rq) ^ xr) * 16);
  const unsigned int bB0 = (unsigned)(16384 + (wm * 64 + col_l) * 128 + ((0 * 4 + rq) ^ xr) * 16);
  const unsigned int bB1 = (unsigned)(16384 + (wm * 64 + col_l) * 128 + ((1 * 4 + rq) ^ xr) * 16);

  f32x4 acc[4][4];   // [e-frag][m-frag]
  #pragma unroll
  for (int i = 0; i < 4; i++)
    #pragma unroll
    for (int j = 0; j < 4; j++)
      #pragma unroll
      for (int q = 0; q < 4; q++) acc[i][j][q] = 0.0f;

  for (int kk = 0; kk < ND; kk += 64) {
    const unsigned short* sA = gA + kk;
    const unsigned short* sB = gB + kk;
    #pragma unroll
    for (int q = 0; q < 4; q++) GLOAD_LDS16(sA + goff[q], smem_b + loff[q]);
    #pragma unroll
    for (int q = 0; q < 4; q++) GLOAD_LDS16(sB + goff[q], smem_b + 16384 + loff[q]);
    __syncthreads();                         // drains vmcnt -> LDS valid
    #pragma unroll
    for (int kkh = 0; kkh < 2; kkh++) {
      const unsigned int aB = kkh ? aB1 : aB0;
      const unsigned int bB = kkh ? bB1 : bB0;
      bf16x8 af[4], bfr[4];
      #pragma unroll
      for (int f = 0; f < 4; f++) {
        af[f]  = __builtin_bit_cast(bf16x8, *(const uint4*)(smem_b + aB + f * 2048));
        bfr[f] = __builtin_bit_cast(bf16x8, *(const uint4*)(smem_b + bB + f * 2048));
      }
      #pragma unroll
      for (int i = 0; i < 4; i++)
        #pragma unroll
        for (int j = 0; j < 4; j++)
          acc[i][j] = __builtin_amdgcn_mfma_f32_16x16x32_bf16(af[i], bfr[j], acc[i][j], 0, 0, 0);
    }
    __syncthreads();                         // protect LDS before next stage
  }

  // epilogue: bias + rope (in-thread pairs) + ushort4 stores
  unsigned short* obuf = (wn == 1) ? kbuf : qbuf;   // wave-uniform
  #pragma unroll
  for (int i = 0; i < 4; i++) {
    const int s0  = i * 16 + rq * 4;
    const int si0 = s0 >> 1;
    float4 bv = *(const float4*)&bias[e0 + wn * 64 + s0];
    #pragma unroll
    for (int j = 0; j < 4; j++) {
      int m   = m0 + wm * 64 + j * 16 + col_l;
      int pos = m & (NL - 1);
      int bb  = m >> 10;
      float c0 = ct[pos * 32 + si0],     n0 = st[pos * 32 + si0];
      float c1 = ct[pos * 32 + si0 + 1], n1 = st[pos * 32 + si0 + 1];
      float v0 = acc[i][j][0] + bv.x;
      float v1 = acc[i][j][1] + bv.y;
      float v2 = acc[i][j][2] + bv.z;
      float v3 = acc[i][j][3] + bv.w;
      ushort4 o;
      o.x = f2bf(v0 * c0 - v1 * n0);
      o.y = f2bf(v1 * c0 + v0 * n0);
      o.z = f2bf(v2 * c1 - v3 * n1);
      o.w = f2bf(v3 * c1 + v2 * n1);
      *(ushort4*)&obuf[(((size_t)(bb * NHEADS + h)) * NL + pos) * HS + s0] = o;
    }
  }
}

// ---- logits: per (b,h) Q @ K^T with masks, /8 ----
// Flat grid 6144, XCD-bijective decode: all 64 tiles of one bh share
// blockIdx%8 (one XCD) -> Q,K of 12 heads (3 MB) stay in that XCD's L2.
__global__ __launch_bounds__(256) void k_logits(
    const unsigned short* __restrict__ qbuf,
    const unsigned short* __restrict__ kbuf,
    const int* __restrict__ mask,
    float* __restrict__ out) {
  const int f  = blockIdx.x;
  const int r  = f & 7, t = f >> 3;
  const int bh = r + 8 * (t >> 6);           // 12 heads per XCD residue
  const int tile = t & 63;
  const int tm = tile >> 3, tn = tile & 7;
  const int b  = bh / NHEADS;
  const int tid  = threadIdx.x;
  const int lane = tid & 63;
  const int w    = tid >> 6;
  const int wm = w >> 1, wn = w & 1;
  const int m_base = tm * 128 + wm * 64;
  const int n_base = tn * 128 + wn * 64;
  const int col_l = lane & 15, rq = lane >> 4;
  const unsigned short* Q = qbuf + (size_t)bh * (NL * HS);
  const unsigned short* K = kbuf + (size_t)bh * (NL * HS);
  const int* mrow = mask + b * NL;

  f32x4 acc[4][4];   // [n-frag][m-frag]
  #pragma unroll
  for (int i = 0; i < 4; i++)
    #pragma unroll
    for (int j = 0; j < 4; j++)
      #pragma unroll
      for (int q = 0; q < 4; q++) acc[i][j][q] = 0.0f;

  #pragma unroll
  for (int ks = 0; ks < 2; ks++) {
    bf16x8 ak[4], bq[4];
    #pragma unroll
    for (int ff = 0; ff < 4; ff++) {
      ak[ff] = load_frag(K + (size_t)(n_base + ff * 16 + col_l) * HS + ks * 32 + rq * 8);
      bq[ff] = load_frag(Q + (size_t)(m_base + ff * 16 + col_l) * HS + ks * 32 + rq * 8);
    }
    #pragma unroll
    for (int i = 0; i < 4; i++)
      #pragma unroll
      for (int j = 0; j < 4; j++)
        acc[i][j] = __builtin_amdgcn_mfma_f32_16x16x32_bf16(ak[i], bq[j], acc[i][j], 0, 0, 0);
  }

  #pragma unroll
  for (int j = 0; j < 4; j++) {
    const int m = m_base + j * 16 + col_l;
    const bool mr0 = (mrow[m] == 0);
    float* orow = out + ((size_t)bh * NL + m) * NL;
    #pragma unroll
    for (int i = 0; i < 4; i++) {
      const int n0 = n_base + i * 16 + rq * 4;
      int4 mc = *(const int4*)&mrow[n0];
      f32x4 o = acc[i][j];
      if (mr0) { o[0] = -INFV; o[1] = -INFV; o[2] = -INFV; o[3] = -INFV; }
      if (mc.x == 0) o[0] = -INFV;
      if (mc.y == 0) o[1] = -INFV;
      if (mc.z == 0) o[2] = -INFV;
      if (mc.w == 0) o[3] = -INFV;
      if (n0 + 0 < m) o[0] -= INFV;
      if (n0 + 1 < m) o[1] -= INFV;
      if (n0 + 2 < m) o[2] -= INFV;
      if (n0 + 3 < m) o[3] -= INFV;
      o *= 0.125f;
      __builtin_nontemporal_store(o, (f32x4*)(orow + n0));
    }
  }
}

extern "C" void kernel_launch(void* const* d_in, const int* in_sizes, int n_in,
                              void* d_out, int out_size, void* d_ws, size_t ws_size,
                              hipStream_t stream) {
  const float* x    = (const float*)d_in[0];
  const float* W    = (const float*)d_in[1];
  const float* bias = (const float*)d_in[2];
  const int*   mask = (const int*)d_in[3];
  float* out = (float*)d_out;
  char* ws = (char*)d_ws;

  unsigned short* xb = (unsigned short*)(ws);              // 12,582,912 B
  unsigned short* wt = (unsigned short*)(ws + 12582912);   //  2,359,296 B
  unsigned short* qb = (unsigned short*)(ws + 14942208);   // 12,582,912 B
  unsigned short* kb = (unsigned short*)(ws + 27525120);   // 12,582,912 B
  float* ct = (float*)(ws + 40108032);                     //    131,072 B
  float* st = (float*)(ws + 40239104);                     //    131,072 B

  k_prep<<<6560, 256, 0, stream>>>(x, W, xb, wt, ct, st);
  k_proj_rope<<<dim3(64, 12), 256, 0, stream>>>(xb, wt, bias, ct, st, qb, kb);
  k_logits<<<6144, 256, 0, stream>>>(qb, kb, mask, out);
}

// Round 5
// 158.412 us; speedup vs baseline: 1.6103x; 1.0860x over previous
//
#include <hip/hip_runtime.h>
#include <hip/hip_bf16.h>
#include <stdint.h>

#define NHEADS 12
#define HS 64
#define NB 8
#define NL 1024
#define ND 768
#define NE 1536
#define INFV 1000000000000.0f

typedef __bf16 bf16x8 __attribute__((ext_vector_type(8)));
typedef float f32x4 __attribute__((ext_vector_type(4)));

typedef __attribute__((address_space(1))) const unsigned int gas_uint;
typedef __attribute__((address_space(3))) unsigned int las_uint;
#define GLOAD_LDS16(g, l) __builtin_amdgcn_global_load_lds((gas_uint*)(g), (las_uint*)(l), 16, 0, 0)

__device__ __forceinline__ unsigned short f2bf(float f) {
  unsigned int u = __builtin_bit_cast(unsigned int, f);
  u += 0x7fffu + ((u >> 16) & 1u);   // round-to-nearest-even
  return (unsigned short)(u >> 16);
}

__device__ __forceinline__ bf16x8 load_frag(const unsigned short* p) {
  uint4 v = *(const uint4*)p;
  return __builtin_bit_cast(bf16x8, v);
}

// ---- fused prep: x->bf16 | W transpose->bf16 | rope trig tables ----
__global__ __launch_bounds__(256) void k_prep(
    const float* __restrict__ x, const float* __restrict__ W,
    unsigned short* __restrict__ xb, unsigned short* __restrict__ wt,
    float* __restrict__ ct, float* __restrict__ st) {
  const int blk = blockIdx.x;
  if (blk < 6144) {
    int i = blk * 256 + threadIdx.x;
    float4 v = ((const float4*)x)[i];
    ushort4 o;
    o.x = f2bf(v.x); o.y = f2bf(v.y); o.z = f2bf(v.z); o.w = f2bf(v.w);
    ((ushort4*)xb)[i] = o;
  } else if (blk < 6144 + 288) {
    __shared__ float tile[64][65];
    int t = blk - 6144;
    int te = t % 24, td = t / 24;
    int c = threadIdx.x & 63, r4 = threadIdx.x >> 6;
    #pragma unroll
    for (int rr = 0; rr < 16; rr++) {
      int row = rr * 4 + r4;
      tile[row][c] = W[(size_t)(td * 64 + row) * NE + te * 64 + c];
    }
    __syncthreads();
    #pragma unroll
    for (int rr = 0; rr < 16; rr++) {
      int row = rr * 4 + r4;
      wt[(size_t)(te * 64 + row) * ND + td * 64 + c] = f2bf(tile[c][row]);
    }
  } else {
    int t = (blk - 6432) * 256 + threadIdx.x;
    int p = t >> 5, i = t & 31;
    float inv = powf(10000.0f, -(float)i / 32.0f);
    float sv, cv;
    sincosf((float)p * inv, &sv, &cv);
    ct[p * 32 + i] = cv;
    st[p * 32 + i] = sv;
  }
}

// ---- proj GEMM (x @ W + b) + RoPE  — m97-style LDS staging, BK=64 ----
__global__ __launch_bounds__(256) void k_proj_rope(
    const unsigned short* __restrict__ xb,   // [8192][768] bf16
    const unsigned short* __restrict__ wt,   // [1536][768] bf16 (W^T)
    const float* __restrict__ bias,          // [1536]
    const float* __restrict__ ct, const float* __restrict__ st,  // [1024][32]
    unsigned short* __restrict__ qbuf, unsigned short* __restrict__ kbuf) {
  const int h  = blockIdx.y;
  const int m0 = blockIdx.x * 128;
  const int e0 = h * 128;
  const int tid  = threadIdx.x;
  const int lane = tid & 63;
  const int w    = tid >> 6;
  const int wm = w >> 1, wn = w & 1;
  const int col_l = lane & 15, rq = lane >> 4;

  __shared__ unsigned short smem[16384];     // 32 KB: A[0,16K) B[16K,32K)
  char* smem_b = (char*)smem;

  unsigned int goff[4], loff[4];
  #pragma unroll
  for (int q = 0; q < 4; q++) {
    int p  = q * 256 + tid;
    int r  = p >> 3, sl = p & 7;
    int s  = sl ^ (r & 7);                   // inverse-swizzled source slot
    goff[q] = r * ND + s * 8;
    loff[q] = p * 16;
  }
  const unsigned short* gA = wt + (size_t)e0 * ND;
  const unsigned short* gB = xb + (size_t)m0 * ND;

  const int xr = col_l & 7;
  const unsigned int aB0 = (unsigned)((wn * 64 + col_l) * 128 + ((0 * 4 + rq) ^ xr) * 16);
  const unsigned int aB1 = (unsigned)((wn * 64 + col_l) * 128 + ((1 * 4 + rq) ^ xr) * 16);
  const unsigned int bB0 = (unsigned)(16384 + (wm * 64 + col_l) * 128 + ((0 * 4 + rq) ^ xr) * 16);
  const unsigned int bB1 = (unsigned)(16384 + (wm * 64 + col_l) * 128 + ((1 * 4 + rq) ^ xr) * 16);

  f32x4 acc[4][4];   // [e-frag][m-frag]
  #pragma unroll
  for (int i = 0; i < 4; i++)
    #pragma unroll
    for (int j = 0; j < 4; j++)
      #pragma unroll
      for (int q = 0; q < 4; q++) acc[i][j][q] = 0.0f;

  for (int kk = 0; kk < ND; kk += 64) {
    const unsigned short* sA = gA + kk;
    const unsigned short* sB = gB + kk;
    #pragma unroll
    for (int q = 0; q < 4; q++) GLOAD_LDS16(sA + goff[q], smem_b + loff[q]);
    #pragma unroll
    for (int q = 0; q < 4; q++) GLOAD_LDS16(sB + goff[q], smem_b + 16384 + loff[q]);
    __syncthreads();
    #pragma unroll
    for (int kkh = 0; kkh < 2; kkh++) {
      const unsigned int aB = kkh ? aB1 : aB0;
      const unsigned int bB = kkh ? bB1 : bB0;
      bf16x8 af[4], bfr[4];
      #pragma unroll
      for (int f = 0; f < 4; f++) {
        af[f]  = __builtin_bit_cast(bf16x8, *(const uint4*)(smem_b + aB + f * 2048));
        bfr[f] = __builtin_bit_cast(bf16x8, *(const uint4*)(smem_b + bB + f * 2048));
      }
      #pragma unroll
      for (int i = 0; i < 4; i++)
        #pragma unroll
        for (int j = 0; j < 4; j++)
          acc[i][j] = __builtin_amdgcn_mfma_f32_16x16x32_bf16(af[i], bfr[j], acc[i][j], 0, 0, 0);
    }
    __syncthreads();
  }

  unsigned short* obuf = (wn == 1) ? kbuf : qbuf;   // wave-uniform
  #pragma unroll
  for (int i = 0; i < 4; i++) {
    const int s0  = i * 16 + rq * 4;
    const int si0 = s0 >> 1;
    float4 bv = *(const float4*)&bias[e0 + wn * 64 + s0];
    #pragma unroll
    for (int j = 0; j < 4; j++) {
      int m   = m0 + wm * 64 + j * 16 + col_l;
      int pos = m & (NL - 1);
      int bb  = m >> 10;
      float c0 = ct[pos * 32 + si0],     n0 = st[pos * 32 + si0];
      float c1 = ct[pos * 32 + si0 + 1], n1 = st[pos * 32 + si0 + 1];
      float v0 = acc[i][j][0] + bv.x;
      float v1 = acc[i][j][1] + bv.y;
      float v2 = acc[i][j][2] + bv.z;
      float v3 = acc[i][j][3] + bv.w;
      ushort4 o;
      o.x = f2bf(v0 * c0 - v1 * n0);
      o.y = f2bf(v1 * c0 + v0 * n0);
      o.z = f2bf(v2 * c1 - v3 * n1);
      o.w = f2bf(v3 * c1 + v2 * n1);
      *(ushort4*)&obuf[(((size_t)(bb * NHEADS + h)) * NL + pos) * HS + s0] = o;
    }
  }
}

// ---- logits: per (b,h) Q @ K^T with masks, /8 ----
// XCD-grouped flat grid. Tiles strictly below the diagonal (tn < tm:
// every element has n < m, causally masked) take a pure fill path with
// v=0 — same mask arithmetic, no Q/K reads, no MFMA. Error |v|/8 << thr.
__global__ __launch_bounds__(256) void k_logits(
    const unsigned short* __restrict__ qbuf,
    const unsigned short* __restrict__ kbuf,
    const int* __restrict__ mask,
    float* __restrict__ out) {
  const int f  = blockIdx.x;
  const int r  = f & 7, t = f >> 3;
  const int bh = r + 8 * (t >> 6);           // 12 heads per XCD residue
  const int tile = t & 63;
  const int tm = tile >> 3, tn = tile & 7;
  const int b  = bh / NHEADS;
  const int tid  = threadIdx.x;
  const int* mrow = mask + b * NL;

  if (tn < tm) {
    // ---- fill path: v = 0, full mask arithmetic, coalesced nt stores ----
    const int n0 = tn * 128 + (tid & 31) * 4;
    int4 mc = *(const int4*)&mrow[n0];
    #pragma unroll
    for (int it = 0; it < 16; it++) {
      int m = tm * 128 + it * 8 + (tid >> 5);
      float mr = (float)mrow[m];
      float base = -INFV * (1.0f - mr);      // v*mr with v=0
      f32x4 o;
      o[0] = ((mc.x ? base : base * 0.0f - INFV) - INFV) * 0.125f;
      o[1] = ((mc.y ? base : base * 0.0f - INFV) - INFV) * 0.125f;
      o[2] = ((mc.z ? base : base * 0.0f - INFV) - INFV) * 0.125f;
      o[3] = ((mc.w ? base : base * 0.0f - INFV) - INFV) * 0.125f;
      __builtin_nontemporal_store(o, (f32x4*)(out + ((size_t)bh * NL + m) * NL + n0));
    }
    return;
  }

  const int lane = tid & 63;
  const int w    = tid >> 6;
  const int wm = w >> 1, wn = w & 1;
  const int m_base = tm * 128 + wm * 64;
  const int n_base = tn * 128 + wn * 64;
  const int col_l = lane & 15, rq = lane >> 4;
  const unsigned short* Q = qbuf + (size_t)bh * (NL * HS);
  const unsigned short* K = kbuf + (size_t)bh * (NL * HS);

  f32x4 acc[4][4];   // [n-frag][m-frag]
  #pragma unroll
  for (int i = 0; i < 4; i++)
    #pragma unroll
    for (int j = 0; j < 4; j++)
      #pragma unroll
      for (int q = 0; q < 4; q++) acc[i][j][q] = 0.0f;

  #pragma unroll
  for (int ks = 0; ks < 2; ks++) {
    bf16x8 ak[4], bq[4];
    #pragma unroll
    for (int ff = 0; ff < 4; ff++) {
      ak[ff] = load_frag(K + (size_t)(n_base + ff * 16 + col_l) * HS + ks * 32 + rq * 8);
      bq[ff] = load_frag(Q + (size_t)(m_base + ff * 16 + col_l) * HS + ks * 32 + rq * 8);
    }
    #pragma unroll
    for (int i = 0; i < 4; i++)
      #pragma unroll
      for (int j = 0; j < 4; j++)
        acc[i][j] = __builtin_amdgcn_mfma_f32_16x16x32_bf16(ak[i], bq[j], acc[i][j], 0, 0, 0);
  }

  #pragma unroll
  for (int j = 0; j < 4; j++) {
    const int m = m_base + j * 16 + col_l;
    const bool mr0 = (mrow[m] == 0);
    float* orow = out + ((size_t)bh * NL + m) * NL;
    #pragma unroll
    for (int i = 0; i < 4; i++) {
      const int n0 = n_base + i * 16 + rq * 4;
      int4 mc = *(const int4*)&mrow[n0];
      f32x4 o = acc[i][j];
      if (mr0) { o[0] = -INFV; o[1] = -INFV; o[2] = -INFV; o[3] = -INFV; }
      if (mc.x == 0) o[0] = -INFV;
      if (mc.y == 0) o[1] = -INFV;
      if (mc.z == 0) o[2] = -INFV;
      if (mc.w == 0) o[3] = -INFV;
      if (n0 + 0 < m) o[0] -= INFV;
      if (n0 + 1 < m) o[1] -= INFV;
      if (n0 + 2 < m) o[2] -= INFV;
      if (n0 + 3 < m) o[3] -= INFV;
      o *= 0.125f;
      __builtin_nontemporal_store(o, (f32x4*)(orow + n0));
    }
  }
}

extern "C" void kernel_launch(void* const* d_in, const int* in_sizes, int n_in,
                              void* d_out, int out_size, void* d_ws, size_t ws_size,
                              hipStream_t stream) {
  const float* x    = (const float*)d_in[0];
  const float* W    = (const float*)d_in[1];
  const float* bias = (const float*)d_in[2];
  const int*   mask = (const int*)d_in[3];
  float* out = (float*)d_out;
  char* ws = (char*)d_ws;

  unsigned short* xb = (unsigned short*)(ws);              // 12,582,912 B
  unsigned short* wt = (unsigned short*)(ws + 12582912);   //  2,359,296 B
  unsigned short* qb = (unsigned short*)(ws + 14942208);   // 12,582,912 B
  unsigned short* kb = (unsigned short*)(ws + 27525120);   // 12,582,912 B
  float* ct = (float*)(ws + 40108032);                     //    131,072 B
  float* st = (float*)(ws + 40239104);                     //    131,072 B

  k_prep<<<6560, 256, 0, stream>>>(x, W, xb, wt, ct, st);
  k_proj_rope<<<dim3(64, 12), 256, 0, stream>>>(xb, wt, bias, ct, st, qb, kb);
  k_logits<<<6144, 256, 0, stream>>>(qb, kb, mask, out);
}

// Round 6
// 127.823 us; speedup vs baseline: 1.9957x; 1.2393x over previous
//
#include <hip/hip_runtime.h>
#include <hip/hip_bf16.h>
#include <stdint.h>

#define NHEADS 12
#define HS 64
#define NB 8
#define NL 1024
#define ND 768
#define NE 1536
#define INFV 1000000000000.0f

typedef __bf16 bf16x8 __attribute__((ext_vector_type(8)));
typedef float f32x4 __attribute__((ext_vector_type(4)));

typedef __attribute__((address_space(1))) const unsigned int gas_uint;
typedef __attribute__((address_space(3))) unsigned int las_uint;
#define GLOAD_LDS16(g, l) __builtin_amdgcn_global_load_lds((gas_uint*)(g), (las_uint*)(l), 16, 0, 0)

__device__ __forceinline__ unsigned short f2bf(float f) {
  unsigned int u = __builtin_bit_cast(unsigned int, f);
  u += 0x7fffu + ((u >> 16) & 1u);   // round-to-nearest-even
  return (unsigned short)(u >> 16);
}

__device__ __forceinline__ bf16x8 load_frag(const unsigned short* p) {
  uint4 v = *(const uint4*)p;
  return __builtin_bit_cast(bf16x8, v);
}

// ---- fused prep: x->bf16 | W transpose->bf16 | rope trig table ----
// cst: [1024 pos][32 si] of float2 (cos, sin) interleaved.
__global__ __launch_bounds__(256) void k_prep(
    const float* __restrict__ x, const float* __restrict__ W,
    unsigned short* __restrict__ xb, unsigned short* __restrict__ wt,
    float* __restrict__ cst) {
  const int blk = blockIdx.x;
  if (blk < 6144) {
    int i = blk * 256 + threadIdx.x;
    float4 v = ((const float4*)x)[i];
    ushort4 o;
    o.x = f2bf(v.x); o.y = f2bf(v.y); o.z = f2bf(v.z); o.w = f2bf(v.w);
    ((ushort4*)xb)[i] = o;
  } else if (blk < 6144 + 288) {
    __shared__ float tile[64][65];
    int t = blk - 6144;
    int te = t % 24, td = t / 24;
    int c = threadIdx.x & 63, r4 = threadIdx.x >> 6;
    #pragma unroll
    for (int rr = 0; rr < 16; rr++) {
      int row = rr * 4 + r4;
      tile[row][c] = W[(size_t)(td * 64 + row) * NE + te * 64 + c];
    }
    __syncthreads();
    #pragma unroll
    for (int rr = 0; rr < 16; rr++) {
      int row = rr * 4 + r4;
      wt[(size_t)(te * 64 + row) * ND + td * 64 + c] = f2bf(tile[c][row]);
    }
  } else {
    int t = (blk - 6432) * 256 + threadIdx.x;   // 32768 = 1024*32
    int p = t >> 5, i = t & 31;
    float inv = powf(10000.0f, -(float)i / 32.0f);
    float sv, cv;
    sincosf((float)p * inv, &sv, &cv);
    cst[(p * 32 + i) * 2 + 0] = cv;
    cst[(p * 32 + i) * 2 + 1] = sv;
  }
}

// ---- proj GEMM (x @ W + b) + RoPE  — m97-style LDS staging, BK=64 ----
__global__ __launch_bounds__(256) void k_proj_rope(
    const unsigned short* __restrict__ xb,   // [8192][768] bf16
    const unsigned short* __restrict__ wt,   // [1536][768] bf16 (W^T)
    const float* __restrict__ bias,          // [1536]
    const float* __restrict__ cst,           // [1024][32] float2 (c,s)
    unsigned short* __restrict__ qbuf, unsigned short* __restrict__ kbuf) {
  const int h  = blockIdx.y;
  const int m0 = blockIdx.x * 128;
  const int e0 = h * 128;
  const int tid  = threadIdx.x;
  const int lane = tid & 63;
  const int w    = tid >> 6;
  const int wm = w >> 1, wn = w & 1;
  const int col_l = lane & 15, rq = lane >> 4;

  __shared__ unsigned short smem[16384];     // 32 KB: A[0,16K) B[16K,32K)
  char* smem_b = (char*)smem;

  unsigned int goff[4], loff[4];
  #pragma unroll
  for (int q = 0; q < 4; q++) {
    int p  = q * 256 + tid;
    int r  = p >> 3, sl = p & 7;
    int s  = sl ^ (r & 7);                   // inverse-swizzled source slot
    goff[q] = r * ND + s * 8;
    loff[q] = p * 16;
  }
  const unsigned short* gA = wt + (size_t)e0 * ND;
  const unsigned short* gB = xb + (size_t)m0 * ND;

  const int xr = col_l & 7;
  const unsigned int aB0 = (unsigned)((wn * 64 + col_l) * 128 + ((0 * 4 + rq) ^ xr) * 16);
  const unsigned int aB1 = (unsigned)((wn * 64 + col_l) * 128 + ((1 * 4 + rq) ^ xr) * 16);
  const unsigned int bB0 = (unsigned)(16384 + (wm * 64 + col_l) * 128 + ((0 * 4 + rq) ^ xr) * 16);
  const unsigned int bB1 = (unsigned)(16384 + (wm * 64 + col_l) * 128 + ((1 * 4 + rq) ^ xr) * 16);

  f32x4 acc[4][4];   // [e-frag][m-frag]
  #pragma unroll
  for (int i = 0; i < 4; i++)
    #pragma unroll
    for (int j = 0; j < 4; j++)
      #pragma unroll
      for (int q = 0; q < 4; q++) acc[i][j][q] = 0.0f;

  for (int kk = 0; kk < ND; kk += 64) {
    const unsigned short* sA = gA + kk;
    const unsigned short* sB = gB + kk;
    #pragma unroll
    for (int q = 0; q < 4; q++) GLOAD_LDS16(sA + goff[q], smem_b + loff[q]);
    #pragma unroll
    for (int q = 0; q < 4; q++) GLOAD_LDS16(sB + goff[q], smem_b + 16384 + loff[q]);
    __syncthreads();
    #pragma unroll
    for (int kkh = 0; kkh < 2; kkh++) {
      const unsigned int aB = kkh ? aB1 : aB0;
      const unsigned int bB = kkh ? bB1 : bB0;
      bf16x8 af[4], bfr[4];
      #pragma unroll
      for (int f = 0; f < 4; f++) {
        af[f]  = __builtin_bit_cast(bf16x8, *(const uint4*)(smem_b + aB + f * 2048));
        bfr[f] = __builtin_bit_cast(bf16x8, *(const uint4*)(smem_b + bB + f * 2048));
      }
      #pragma unroll
      for (int i = 0; i < 4; i++)
        #pragma unroll
        for (int j = 0; j < 4; j++)
          acc[i][j] = __builtin_amdgcn_mfma_f32_16x16x32_bf16(af[i], bfr[j], acc[i][j], 0, 0, 0);
    }
    __syncthreads();
  }

  // epilogue: bias + rope (in-thread pairs, one 16B trig load per frag)
  unsigned short* obuf = (wn == 1) ? kbuf : qbuf;   // wave-uniform
  #pragma unroll
  for (int j = 0; j < 4; j++) {
    const int m   = m0 + wm * 64 + j * 16 + col_l;
    const int pos = m & (NL - 1);
    const int bb  = m >> 10;
    const float* crow = cst + pos * 64;
    unsigned short* orow = obuf + (((size_t)(bb * NHEADS + h)) * NL + pos) * HS;
    #pragma unroll
    for (int i = 0; i < 4; i++) {
      const int s0 = i * 16 + rq * 4;
      float4 bv = *(const float4*)&bias[e0 + wn * 64 + s0];
      float4 tq = *(const float4*)(crow + s0 * 2);   // (c0,s0,c1,s1) for pair si0,si0+1
      float v0 = acc[i][j][0] + bv.x;
      float v1 = acc[i][j][1] + bv.y;
      float v2 = acc[i][j][2] + bv.z;
      float v3 = acc[i][j][3] + bv.w;
      ushort4 o;
      o.x = f2bf(v0 * tq.x - v1 * tq.y);
      o.y = f2bf(v1 * tq.x + v0 * tq.y);
      o.z = f2bf(v2 * tq.z - v3 * tq.w);
      o.w = f2bf(v3 * tq.z + v2 * tq.w);
      *(ushort4*)&orow[s0] = o;
    }
  }
}

// ---- logits: per (b,h) Q @ K^T with masks, /8 ----
// XCD-grouped flat grid; below-diag tiles -> fill path; compute tiles
// use an LDS-bounce epilogue: acc -> padded LDS -> row-major readback
// with vectorized masks -> 512B-contiguous NT stores.
__global__ __launch_bounds__(256) void k_logits(
    const unsigned short* __restrict__ qbuf,
    const unsigned short* __restrict__ kbuf,
    const int* __restrict__ mask,
    float* __restrict__ out) {
  const int f  = blockIdx.x;
  const int r  = f & 7, t = f >> 3;
  const int bh = r + 8 * (t >> 6);           // 12 heads per XCD residue
  const int tile = t & 63;
  const int tm = tile >> 3, tn = tile & 7;
  const int b  = bh / NHEADS;
  const int tid  = threadIdx.x;
  const int* mrow = mask + b * NL;

  if (tn < tm) {
    // ---- fill path: v = 0, full mask arithmetic, coalesced nt stores ----
    const int n0 = tn * 128 + (tid & 31) * 4;
    int4 mc = *(const int4*)&mrow[n0];
    #pragma unroll
    for (int it = 0; it < 16; it++) {
      int m = tm * 128 + it * 8 + (tid >> 5);
      float mr = (float)mrow[m];
      float base = -INFV * (1.0f - mr);      // v*mr with v=0
      f32x4 o;
      o[0] = ((mc.x ? base : -INFV) - INFV) * 0.125f;
      o[1] = ((mc.y ? base : -INFV) - INFV) * 0.125f;
      o[2] = ((mc.z ? base : -INFV) - INFV) * 0.125f;
      o[3] = ((mc.w ? base : -INFV) - INFV) * 0.125f;
      __builtin_nontemporal_store(o, (f32x4*)(out + ((size_t)bh * NL + m) * NL + n0));
    }
    return;
  }

  const int lane = tid & 63;
  const int w    = tid >> 6;
  const int wm = w >> 1, wn = w & 1;
  const int m_base = tm * 128 + wm * 64;
  const int n_base = tn * 128 + wn * 64;
  const int col_l = lane & 15, rq = lane >> 4;
  const unsigned short* Q = qbuf + (size_t)bh * (NL * HS);
  const unsigned short* K = kbuf + (size_t)bh * (NL * HS);

  __shared__ float lds[64 * 132];            // 33792 B, +4 float row pad

  f32x4 acc[4][4];   // [n-frag][m-frag]
  #pragma unroll
  for (int i = 0; i < 4; i++)
    #pragma unroll
    for (int j = 0; j < 4; j++)
      #pragma unroll
      for (int q = 0; q < 4; q++) acc[i][j][q] = 0.0f;

  #pragma unroll
  for (int ks = 0; ks < 2; ks++) {
    bf16x8 ak[4], bq[4];
    #pragma unroll
    for (int ff = 0; ff < 4; ff++) {
      ak[ff] = load_frag(K + (size_t)(n_base + ff * 16 + col_l) * HS + ks * 32 + rq * 8);
      bq[ff] = load_frag(Q + (size_t)(m_base + ff * 16 + col_l) * HS + ks * 32 + rq * 8);
    }
    #pragma unroll
    for (int i = 0; i < 4; i++)
      #pragma unroll
      for (int j = 0; j < 4; j++)
        acc[i][j] = __builtin_amdgcn_mfma_f32_16x16x32_bf16(ak[i], bq[j], acc[i][j], 0, 0, 0);
  }

  // ---- LDS-bounce epilogue: two passes over the m-halves of the tile ----
  const bool diag = (tn == tm);
  const int rb_row = tid >> 5;               // 0..7 readback row within group
  const int rb_c4  = (tid & 31) * 4;         // 0..124 readback col (floats)
  const int n_rb   = tn * 128 + rb_c4;
  int4 mc_rb = *(const int4*)&mrow[n_rb];
  const bool allmc = (mc_rb.x & mc_rb.y & mc_rb.z & mc_rb.w) != 0;

  #pragma unroll
  for (int pass = 0; pass < 2; pass++) {
    if (wm == pass) {
      #pragma unroll
      for (int j = 0; j < 4; j++) {
        const int rl = j * 16 + col_l;       // local row 0..63
        #pragma unroll
        for (int i = 0; i < 4; i++)
          *(f32x4*)&lds[rl * 132 + wn * 64 + i * 16 + rq * 4] = acc[i][j];
      }
    }
    __syncthreads();
    #pragma unroll
    for (int it = 0; it < 8; it++) {
      const int rl = it * 8 + rb_row;        // local row 0..63
      const int m  = tm * 128 + pass * 64 + rl;
      f32x4 v = *(const f32x4*)&lds[rl * 132 + rb_c4];
      if (mrow[m] == 0) { v[0] = -INFV; v[1] = -INFV; v[2] = -INFV; v[3] = -INFV; }
      if (!allmc) {
        if (mc_rb.x == 0) v[0] = -INFV;
        if (mc_rb.y == 0) v[1] = -INFV;
        if (mc_rb.z == 0) v[2] = -INFV;
        if (mc_rb.w == 0) v[3] = -INFV;
      }
      if (diag) {
        if (n_rb + 0 < m) v[0] -= INFV;
        if (n_rb + 1 < m) v[1] -= INFV;
        if (n_rb + 2 < m) v[2] -= INFV;
        if (n_rb + 3 < m) v[3] -= INFV;
      }
      v *= 0.125f;
      __builtin_nontemporal_store(v, (f32x4*)(out + ((size_t)bh * NL + m) * NL + n_rb));
    }
    __syncthreads();
  }
}

extern "C" void kernel_launch(void* const* d_in, const int* in_sizes, int n_in,
                              void* d_out, int out_size, void* d_ws, size_t ws_size,
                              hipStream_t stream) {
  const float* x    = (const float*)d_in[0];
  const float* W    = (const float*)d_in[1];
  const float* bias = (const float*)d_in[2];
  const int*   mask = (const int*)d_in[3];
  float* out = (float*)d_out;
  char* ws = (char*)d_ws;

  unsigned short* xb = (unsigned short*)(ws);              // 12,582,912 B
  unsigned short* wt = (unsigned short*)(ws + 12582912);   //  2,359,296 B
  unsigned short* qb = (unsigned short*)(ws + 14942208);   // 12,582,912 B
  unsigned short* kb = (unsigned short*)(ws + 27525120);   // 12,582,912 B
  float* cst = (float*)(ws + 40108032);                    //    262,144 B

  k_prep<<<6560, 256, 0, stream>>>(x, W, xb, wt, cst);
  k_proj_rope<<<dim3(64, 12), 256, 0, stream>>>(xb, wt, bias, cst, qb, kb);
  k_logits<<<6144, 256, 0, stream>>>(qb, kb, mask, out);
}